// Round 1
// 1036.385 us; speedup vs baseline: 1.0466x; 1.0466x over previous
//
#include <hip/hip_runtime.h>
#include <math.h>

// ---- problem dims ----
// NX=128 NY=64 NM=32 NDT=32 NU=32 ND=32  N_STEPS=1024 B=128 TP=64
// chunked scan: 64 chunks x 16 steps

// ---- output offsets (float elements) ----
#define OUT_X      0
#define OUT_Y      16777216
#define OUT_U      25165824
#define OUT_SXMIN  29360128
#define OUT_SXMAX  46137344
#define OUT_SUMIN  62914560
#define OUT_SUMAX  67108864
#define OUT_SDXX   71303168
#define OUT_SDXU   88080384
#define OUT_SDXD   104857600
#define OUT_SPECT  121634816

// ---- workspace offsets (bytes) ----
#define WS_WA     0          // f32 [128][128] W_A row-major
#define WS_APOW   65536      // fp16 col-major A^k, slot k at WS_APOW+(k-1)*32768, k=1..16
#define WS_WC     589824     // fp16 col-major [n=64][k=128]
#define WS_WB     606208     // fp16 col-major [n=128][k=32]
#define WS_WE     614400     // fp16 col-major [n=128][k=32]
#define WS_WHF    622592     // fp16 [i=32][o=32][j=32]
#define WS_R      688128     // f32 [128]  r = x0_correct @ W_A
#define WS_ERRP   688640     // f32 [64] per-wg spect-err partials
#define WS_Z      1048576    // f32 [64][128][128] chunk-boundary states (slot 0 = x0)
#define WS_C      5242880    // fp16 tiled c_t: [t][mt8][nt8][lane64][reg4]
#define WS_XLOC   38797312   // fp16 tiled local-scan states, same layout
// total ws need ~72.4 MB

// LDS row stride for 128-wide fp16 transpose tiles: 136 halves = 272 B
#define XSTR 136

typedef _Float16 half8  __attribute__((ext_vector_type(8)));
typedef _Float16 half4v __attribute__((ext_vector_type(4)));
typedef float    floatx4 __attribute__((ext_vector_type(4)));

#define MFMA16(a,b,c) __builtin_amdgcn_mfma_f32_16x16x32_f16((a),(b),(c),0,0,0)

__device__ __forceinline__ float sigm(float x){ return 1.0f/(1.0f+expf(-x)); }
__device__ __forceinline__ float gelu_t(float x){
  float u = 0.7978845608028654f*(x + 0.044715f*x*x*x);
  return 0.5f*x*(1.0f+tanhf(u));
}
// load 8 consecutive f32 (32B-aligned) -> half8
__device__ __forceinline__ half8 ldg8h(const float* p){
  const floatx4* p4 = (const floatx4*)p;
  floatx4 a = p4[0], b = p4[1];
  half8 r;
  r[0]=(_Float16)a[0]; r[1]=(_Float16)a[1]; r[2]=(_Float16)a[2]; r[3]=(_Float16)a[3];
  r[4]=(_Float16)b[0]; r[5]=(_Float16)b[1]; r[6]=(_Float16)b[2]; r[7]=(_Float16)b[3];
  return r;
}
// load 8 f32 scalars (LDS, arbitrary 4B align) -> half8
__device__ __forceinline__ half8 lds8h(const float* p){
  half8 r;
  #pragma unroll
  for (int e=0;e<8;e++) r[e] = (_Float16)p[e];
  return r;
}
__device__ __forceinline__ floatx4 h4f4(half4v h){
  floatx4 f; f[0]=(float)h[0]; f[1]=(float)h[1]; f[2]=(float)h[2]; f[3]=(float)h[3]; return f;
}
__device__ __forceinline__ half4v f4h4(floatx4 f){
  half4v h; h[0]=(_Float16)f[0]; h[1]=(_Float16)f[1]; h[2]=(_Float16)f[2]; h[3]=(_Float16)f[3]; return h;
}

// =====================================================================
// K1: blocks 0..63  : weight prep + spectral-error (wave-dot, coalesced)
//     blocks 64..191: per-batch RNN (fp32) -> z[0] = x0
// grid 192 x 256
// =====================================================================
__global__ __launch_bounds__(256,1) void k1_weights(
    const float* __restrict__ U_A, const float* __restrict__ sig_A, const float* __restrict__ V_A,
    const float* __restrict__ U_C, const float* __restrict__ sig_C, const float* __restrict__ V_C,
    const float* __restrict__ w_E, const float* __restrict__ s_E,  const float* __restrict__ w_B,
    const float* __restrict__ W_hf,
    const float* __restrict__ Ym, const float* __restrict__ W_ih, const float* __restrict__ W_hh,
    char* __restrict__ ws)
{
  int tid = threadIdx.x, bid = blockIdx.x;

  if (bid >= 64){
    // ---------------- RNN: one batch per block ----------------
    int b = bid - 64;                     // 0..127
    __shared__ float ybAll[4096];         // Ym[t][b][:] for all t
    __shared__ float hbuf[2][128];
    for (int e=tid; e<4096; e+=256)
      ybAll[e] = Ym[(e>>6)*8192 + b*64 + (e&63)];
    if (tid < 128) hbuf[0][tid] = 0.f;
    float wih[64], whh[128];
    if (tid < 128){
      #pragma unroll
      for (int k=0;k<64;k++)  wih[k] = W_ih[k*128+tid];
      #pragma unroll
      for (int k=0;k<128;k++) whh[k] = W_hh[k*128+tid];
    }
    __syncthreads();
    int cur = 0;
    for (int t=0;t<64;t++){
      if (tid < 128){
        const float* yb = &ybAll[t*64];
        const float* hb = hbuf[cur];
        float a0=0.f,a1=0.f,a2=0.f,a3=0.f;
        #pragma unroll
        for (int k=0;k<64;k+=4){
          a0 += yb[k]  *wih[k];   a1 += yb[k+1]*wih[k+1];
          a2 += yb[k+2]*wih[k+2]; a3 += yb[k+3]*wih[k+3];
        }
        #pragma unroll
        for (int k=0;k<128;k+=4){
          a0 += hb[k]  *whh[k];   a1 += hb[k+1]*whh[k+1];
          a2 += hb[k+2]*whh[k+2]; a3 += hb[k+3]*whh[k+3];
        }
        hbuf[cur^1][tid] = gelu_t((a0+a1)+(a2+a3));
      }
      __syncthreads();
      cur ^= 1;
    }
    if (tid < 128){
      float* z0 = (float*)(ws + WS_Z);
      z0[b*128 + tid] = hbuf[cur][tid];
    }
    return;
  }

  // ---------------- weight prep (blocks 0..63) ----------------
  __shared__ float sA[128];
  __shared__ float sC[64];
  __shared__ float redw[4];
  if (tid < 128) sA[tid] = 0.1f + 0.8f*sigm(sig_A[tid]);
  else if (tid < 192) sC[tid-128] = 0.9f + 0.1f*sigm(sig_C[tid-128]);
  __syncthreads();

  float*     wa  = (float*)(ws + WS_WA);
  _Float16*  ap1 = (_Float16*)(ws + WS_APOW);            // slot 1 (col-major)
  _Float16*  wc  = (_Float16*)(ws + WS_WC);
  _Float16*  wb  = (_Float16*)(ws + WS_WB);
  _Float16*  we  = (_Float16*)(ws + WS_WE);
  _Float16*  whf = (_Float16*)(ws + WS_WHF);
  float*     errp= (float*)(ws + WS_ERRP);

  // W_A = U_A @ diag(sA) @ V_A : one elem per thread
  {
    int e = bid*256 + tid;               // 0..16383
    int i = e >> 7, j = e & 127;
    float acc = 0.f;
    for (int k=0;k<128;k++) acc += U_A[i*128+k]*sA[k]*V_A[k*128+j];
    wa[i*128+j] = acc;
    ap1[j*128+i] = (_Float16)acc;        // col-major fp16 (B-operand layout)
  }
  if (bid < 16){
    // W_C = (U_C[:, :64] * sC) @ V_C  -> col-major fp16 [n][k=128]
    #pragma unroll
    for (int rep=0;rep<2;rep++){
      int e = bid*512 + rep*256 + tid;   // 0..8191
      int i = e >> 6, n = e & 63;
      float acc = 0.f;
      for (int k=0;k<64;k++) acc += U_C[i*128+k]*sC[k]*V_C[k*64+n];
      wc[n*128+i] = (_Float16)acc;
    }
  } else if (bid == 16){
    if (tid < 128){
      int j = tid;                       // column of (32,128)
      float mx = -1e30f;
      for (int i=0;i<32;i++) mx = fmaxf(mx, w_E[i*128+j]);
      float ex[32]; float sm = 0.f;
      for (int i=0;i<32;i++){ ex[i] = expf(w_E[i*128+j]-mx); sm += ex[i]; }
      for (int i=0;i<32;i++){
        float s = 1.0f - 0.95f*sigm(s_E[i*128+j]);
        we[j*32+i] = (_Float16)(s*ex[i]/sm);
      }
    }
  } else if (bid == 17){
    if (tid < 128){
      int n = tid;
      for (int k=0;k<32;k++) wb[n*32+k] = (_Float16)fmaxf(w_B[k*128+n], 0.f);
    }
  } else if (bid == 18){
    // W_hf (o,i,j) -> fp16 [i][o][j]
    for (int rep=0;rep<128;rep++){
      int e = rep*256 + tid;             // 0..32767
      int o = e >> 10, i = (e>>5)&31, j = e & 31;
      whf[i*1024 + o*32 + j] = (_Float16)W_hf[e];
    }
  }

  // spectral-error: one dot per wave, coalesced row loads + butterfly reduce.
  // 53248 dots = 256 waves x 208
  {
    int wv = tid>>6, lane = tid&63;
    float part = 0.f;
    int dbase = (bid*4 + wv)*208;
    for (int l=0;l<208;l++){
      int d = dbase + l;
      const float* Mp; int i, j, K; float inv;
      if (d < 16384){ Mp=U_A; i=d>>7; j=d&127; K=128; inv=1.f/16384.f; }
      else if (d < 32768){ Mp=V_A; int dd=d-16384; i=dd>>7; j=dd&127; K=128; inv=1.f/16384.f; }
      else if (d < 49152){ Mp=U_C; int dd=d-32768; i=dd>>7; j=dd&127; K=128; inv=1.f/16384.f; }
      else { Mp=V_C; int dd=d-49152; i=dd>>6; j=dd&63; K=64; inv=1.f/4096.f; }
      float p;
      if (K == 128){
        float2 a = ((const float2*)(Mp + i*128))[lane];
        float2 b = ((const float2*)(Mp + j*128))[lane];
        p = a.x*b.x + a.y*b.y;
      } else {
        p = Mp[i*64+lane]*Mp[j*64+lane];
      }
      #pragma unroll
      for (int m=1;m<64;m<<=1) p += __shfl_xor(p, m, 64);
      float cdf = p - (i==j ? 1.f : 0.f);
      part += cdf*cdf*inv;
    }
    if (lane == 0) redw[wv] = part;
  }
  __syncthreads();
  if (tid == 0) errp[bid] = redw[0]+redw[1]+redw[2]+redw[3];
}

// =====================================================================
// K1b: finalize spect err, write SpectErr output, compute r = x0c @ W_A
// =====================================================================
__global__ __launch_bounds__(256) void k1b_finalize(
    const float* __restrict__ x0c, char* __restrict__ ws, float* __restrict__ out)
{
  int tid = threadIdx.x;
  const float* errp = (const float*)(ws + WS_ERRP);
  const float* wa   = (const float*)(ws + WS_WA);
  float*       rws  = (float*)(ws + WS_R);
  __shared__ float red[64];
  if (tid < 64) red[tid] = errp[tid];
  __syncthreads();
  if (tid == 0){
    float s = 0.f;
    for (int i=0;i<64;i++) s += red[i];
    red[0] = s;
  }
  __syncthreads();
  float spect = red[0];
  for (int r = tid; r < 1024; r += 256) out[OUT_SPECT + r] = spect;
  if (tid < 128){
    float a = 0.f;
    for (int k=0;k<128;k++) a += x0c[k]*wa[k*128+tid];
    rws[tid] = a;
  }
}

// =====================================================================
// K3: blocks 0..1023: per-t forcing: u (bilinear), Bu, Ed; outputs
//     U/Sumin/Sumax/dx_u/dx_d; c_t -> tiled fp16 ws.
//     block 1024: sequential power chain A^2..A^16 (fp16 MFMA), hidden
//     under the forcing blocks.
// grid 1025 x 256
// =====================================================================
__global__ __launch_bounds__(256,2) void k3_forcing(
    const float* __restrict__ Mf, const float* __restrict__ pDT, const float* __restrict__ pD,
    const float* __restrict__ pUMIN, const float* __restrict__ pUMAX,
    const float* __restrict__ pdxmin, const float* __restrict__ pdxmax,
    char* __restrict__ ws, float* __restrict__ out)
{
  int tid = threadIdx.x;
  int wave = tid>>6, lane = tid&63, l15 = lane&15, q = lane>>4;
  __shared__ __align__(16) float smemf[8960];   // 35840 B union

  if (blockIdx.x == 1024){
    // ---------------- power chain: P^{p} = P^{p-1} @ A ----------------
    if (tid >= 128) return;                      // waves 0,1 only; no barriers below
    _Float16* xl2 = (_Float16*)smemf;            // [2][64*XSTR] halves = 34816 B
    const float*    wa = (const float*)(ws + WS_WA);
    const _Float16* a1 = (const _Float16*)(ws + WS_APOW);
    half8 af[4][4];
    #pragma unroll
    for (int mt=0;mt<4;mt++)
      #pragma unroll
      for (int kt=0;kt<4;kt++)
        af[mt][kt] = ldg8h(wa + (wave*64+mt*16+l15)*128 + kt*32 + q*8);
    for (int p=2;p<=16;p++){
      _Float16* dst = (_Float16*)(ws + WS_APOW + (p-1)*32768);
      for (int nt=0;nt<8;nt++){
        floatx4 acc[4];
        #pragma unroll
        for (int mt=0;mt<4;mt++){ acc[mt][0]=0.f; acc[mt][1]=0.f; acc[mt][2]=0.f; acc[mt][3]=0.f; }
        #pragma unroll
        for (int kt=0;kt<4;kt++){
          half8 bfv = *(const half8*)(a1 + (nt*16+l15)*128 + kt*32 + q*8);
          #pragma unroll
          for (int mt=0;mt<4;mt++) acc[mt] = MFMA16(af[mt][kt], bfv, acc[mt]);
        }
        #pragma unroll
        for (int mt=0;mt<4;mt++){
          half4v hv = f4h4(acc[mt]);
          int mg = wave*64 + mt*16;
          *(half4v*)(dst + (nt*16+l15)*128 + mg + q*4) = hv;   // col-major [n][m]
          #pragma unroll
          for (int r=0;r<4;r++) xl2[wave*(64*XSTR) + (mt*16+q*4+r)*XSTR + nt*16+l15] = hv[r];
        }
      }
      #pragma unroll
      for (int mt=0;mt<4;mt++)
        #pragma unroll
        for (int kt=0;kt<4;kt++)
          af[mt][kt] = *(const half8*)(&xl2[wave*(64*XSTR) + (mt*16+l15)*XSTR + kt*32 + q*8]);
    }
    return;
  }

  // ---------------- forcing ----------------
  int t = blockIdx.x;
  float* mls = smemf;                    // [128*33] = 4224 f
  float* uls = smemf + 4224;             // [4][32*34] = 4352 f, wave stride 1088
  float* rls = smemf + 8576;             // [128]
  float* dmn = smemf + 8704;             // [128]
  float* dmx = smemf + 8832;             // [128]

  const float* rws = (const float*)(ws + WS_R);
  for (int e=tid; e<4096; e+=256){
    float v = Mf[t*4096 + e];
    mls[(e>>5)*33 + (e&31)] = v;
  }
  if (tid < 128){ rls[tid]=rws[tid]; dmn[tid]=pdxmin[tid]; dmx[tid]=pdxmax[tid]; }
  __syncthreads();

  int b0 = wave*32 + l15;
  int b1 = wave*32 + 16 + l15;
  half8 dtf0 = ldg8h(pDT + t*4096 + b0*32 + q*8);
  half8 dtf1 = ldg8h(pDT + t*4096 + b1*32 + q*8);
  half8 ddf0 = ldg8h(pD  + t*4096 + b0*32 + q*8);
  half8 ddf1 = ldg8h(pD  + t*4096 + b1*32 + q*8);

  const _Float16* whf = (const _Float16*)(ws + WS_WHF);
  floatx4 u00,u01,u10,u11;
  u00[0]=u00[1]=u00[2]=u00[3]=0.f; u01=u00; u10=u00; u11=u00;
  for (int i=0;i<32;i++){
    _Float16 m0 = (_Float16)mls[b0*33 + i];
    _Float16 m1 = (_Float16)mls[b1*33 + i];
    half8 a0, a1;
    #pragma unroll
    for (int e=0;e<8;e++){ a0[e] = dtf0[e]*m0; a1[e] = dtf1[e]*m1; }
    half8 bo0 = *(const half8*)(whf + i*1024 + l15*32      + q*8);
    half8 bo1 = *(const half8*)(whf + i*1024 + (16+l15)*32 + q*8);
    u00 = MFMA16(a0, bo0, u00); u01 = MFMA16(a0, bo1, u01);
    u10 = MFMA16(a1, bo0, u10); u11 = MFMA16(a1, bo1, u11);
  }
  // u outputs + stage u in LDS (A-frag source for Bu)
  #pragma unroll
  for (int mt=0;mt<2;mt++){
    #pragma unroll
    for (int nto=0;nto<2;nto++){
      floatx4 uacc = mt ? (nto?u11:u10) : (nto?u01:u00);
      #pragma unroll
      for (int r=0;r<4;r++){
        int b = wave*32 + mt*16 + q*4 + r;
        int o = nto*16 + l15;
        int ub = t*4096 + b*32 + o;
        float uv = uacc[r];
        __builtin_nontemporal_store(uv, &out[OUT_U + ub]);
        __builtin_nontemporal_store(fmaxf(__builtin_nontemporal_load(&pUMIN[ub])-uv, 0.f), &out[OUT_SUMIN + ub]);
        __builtin_nontemporal_store(fmaxf(uv-__builtin_nontemporal_load(&pUMAX[ub]), 0.f), &out[OUT_SUMAX + ub]);
        uls[wave*1088 + (mt*16+q*4+r)*34 + o] = uv;
      }
    }
  }
  // same-wave LDS write->read; no barrier needed
  half8 uf0 = lds8h(&uls[wave*1088 + (l15)*34 + q*8]);
  half8 uf1 = lds8h(&uls[wave*1088 + (16+l15)*34 + q*8]);

  const _Float16* wb = (const _Float16*)(ws + WS_WB);
  const _Float16* we = (const _Float16*)(ws + WS_WE);
  _Float16* cws = (_Float16*)(ws + WS_C);
  for (int nt=0; nt<8; nt++){
    half8 wbf = *(const half8*)(wb + (nt*16+l15)*32 + q*8);
    half8 wef = *(const half8*)(we + (nt*16+l15)*32 + q*8);
    floatx4 zz; zz[0]=zz[1]=zz[2]=zz[3]=0.f;
    floatx4 bu0=MFMA16(uf0, wbf, zz), bu1=MFMA16(uf1, wbf, zz);
    floatx4 ed0=MFMA16(ddf0, wef, zz), ed1=MFMA16(ddf1, wef, zz);
    int col = nt*16 + l15;
    float dn = dmn[col], dxv = dmx[col], rv = rls[col];
    #pragma unroll
    for (int mt=0;mt<2;mt++){
      floatx4 bu = mt?bu1:bu0, ed = mt?ed1:ed0;
      half4v cp;
      #pragma unroll
      for (int r=0;r<4;r++){
        int b = wave*32 + mt*16 + q*4 + r;
        int base = t*16384 + b*128 + col;
        float buv = bu[r], edv = ed[r];
        __builtin_nontemporal_store(fmaxf(dn-buv,0.f) + fmaxf(buv-dxv,0.f), &out[OUT_SDXU + base]);
        __builtin_nontemporal_store(fmaxf(dn-edv,0.f) + fmaxf(edv-dxv,0.f), &out[OUT_SDXD + base]);
        cp[r] = (_Float16)(rv + buv + edv);
      }
      *(half4v*)(cws + (((t*8 + (wave*2+mt))*8 + nt)<<8) + lane*4) = cp;
    }
  }
}

// =====================================================================
// K5a: pass1 local scans (zero-init), 64 chunks x 16 steps.
// grid 512 x 64 : one wave per (chunk = bid>>3, b-tile = bid&7);
// next-step c_t prefetched into registers to pull HBM latency off the
// serial MFMA->LDS critical path.
// =====================================================================
__global__ __launch_bounds__(64,1) void k5a_pass1(char* __restrict__ ws)
{
  int lane = threadIdx.x, l15 = lane&15, q = lane>>4;
  int chunk = blockIdx.x >> 3, mt_g = blockIdx.x & 7;
  const _Float16* a1   = (const _Float16*)(ws + WS_APOW);
  const _Float16* cws  = (const _Float16*)(ws + WS_C);
  _Float16*       xloc = (_Float16*)(ws + WS_XLOC);
  __shared__ _Float16 xl[16*XSTR];

  half8 bf[8][4];
  #pragma unroll
  for (int nt=0;nt<8;nt++)
    #pragma unroll
    for (int kt=0;kt<4;kt++)
      bf[nt][kt] = *(const half8*)(a1 + (nt*16+l15)*128 + kt*32 + q*8);
  half8 af[4] = {};                               // x starts at 0

  int t0 = chunk*16;
  half4v cv[8];
  #pragma unroll
  for (int nt=0;nt<8;nt++)
    cv[nt] = *(const half4v*)(cws + (((t0*8+mt_g)*8+nt)<<8) + lane*4);

  for (int s=0;s<16;s++){
    int t = t0 + s;
    floatx4 acc[8];
    #pragma unroll
    for (int nt=0;nt<8;nt++) acc[nt] = h4f4(cv[nt]);
    if (s < 15){
      #pragma unroll
      for (int nt=0;nt<8;nt++)
        cv[nt] = *(const half4v*)(cws + ((((t+1)*8+mt_g)*8+nt)<<8) + lane*4);
    }
    #pragma unroll
    for (int kt=0;kt<4;kt++)
      #pragma unroll
      for (int nt=0;nt<8;nt++)
        acc[nt] = MFMA16(af[kt], bf[nt][kt], acc[nt]);
    #pragma unroll
    for (int nt=0;nt<8;nt++){
      half4v hv = f4h4(acc[nt]);
      *(half4v*)(xloc + (((t*8+mt_g)*8+nt)<<8) + lane*4) = hv;
      #pragma unroll
      for (int r=0;r<4;r++) xl[(q*4+r)*XSTR + nt*16+l15] = hv[r];
    }
    #pragma unroll
    for (int kt=0;kt<4;kt++)
      af[kt] = *(const half8*)(&xl[l15*XSTR + kt*32 + q*8]);
  }
}

// =====================================================================
// K5b: boundary scan z_{c+1} = z_c @ A^16 + Xloc[16c+15].
// grid 8 x 64 : one wave per 16-row b-tile, 63 serial steps;
// next-step Xloc tile prefetched into registers.
// =====================================================================
__global__ __launch_bounds__(64,1) void k5b_boundary(char* __restrict__ ws)
{
  int lane = threadIdx.x, l15 = lane&15, q = lane>>4;
  int mt_g = blockIdx.x;
  const _Float16* a16  = (const _Float16*)(ws + WS_APOW + 15*32768);
  const _Float16* xloc = (const _Float16*)(ws + WS_XLOC);
  float*          z    = (float*)(ws + WS_Z);
  __shared__ _Float16 xl[16*XSTR];

  half8 bf[8][4];
  #pragma unroll
  for (int nt=0;nt<8;nt++)
    #pragma unroll
    for (int kt=0;kt<4;kt++)
      bf[nt][kt] = *(const half8*)(a16 + (nt*16+l15)*128 + kt*32 + q*8);
  half8 af[4];
  #pragma unroll
  for (int kt=0;kt<4;kt++)
    af[kt] = ldg8h(z + (mt_g*16+l15)*128 + kt*32 + q*8);   // z_0 = x0

  half4v pf[8];
  #pragma unroll
  for (int nt=0;nt<8;nt++)
    pf[nt] = *(const half4v*)(xloc + (((15*8+mt_g)*8+nt)<<8) + lane*4);

  for (int c=0;c<63;c++){
    floatx4 acc[8];
    #pragma unroll
    for (int nt=0;nt<8;nt++) acc[nt] = h4f4(pf[nt]);
    if (c < 62){
      int tn = (c+1)*16 + 15;
      #pragma unroll
      for (int nt=0;nt<8;nt++)
        pf[nt] = *(const half4v*)(xloc + (((tn*8+mt_g)*8+nt)<<8) + lane*4);
    }
    #pragma unroll
    for (int kt=0;kt<4;kt++)
      #pragma unroll
      for (int nt=0;nt<8;nt++)
        acc[nt] = MFMA16(af[kt], bf[nt][kt], acc[nt]);
    #pragma unroll
    for (int nt=0;nt<8;nt++){
      #pragma unroll
      for (int r=0;r<4;r++){
        int b = mt_g*16 + q*4 + r;
        z[(c+1)*16384 + b*128 + nt*16+l15] = acc[nt][r];
        xl[(q*4+r)*XSTR + nt*16+l15] = (_Float16)acc[nt][r];
      }
    }
    #pragma unroll
    for (int kt=0;kt<4;kt++)
      af[kt] = *(const half8*)(&xl[l15*XSTR + kt*32 + q*8]);
  }
}

// =====================================================================
// K6: wide correction + epilogue. X_t = Xloc_t + z_c @ A^{k+1};
//     X_{t-1} analogous (A^k, or z itself at k=0); y = X_t @ W_C; slacks.
//     Output streams use nontemporal stores; XMIN/XMAX nontemporal loads
//     (read-once) to keep L2 for xloc / A^k / z reuse.
// grid 1024 x 256
// =====================================================================
__global__ __launch_bounds__(256,2) void k6_epilogue(
    const float* __restrict__ pXMIN, const float* __restrict__ pXMAX,
    char* __restrict__ ws, float* __restrict__ out)
{
  int t = blockIdx.x, tid = threadIdx.x;
  int wave = tid>>6, lane = tid&63, l15 = lane&15, q = lane>>4;
  int c = t>>4, k = t&15;
  __shared__ _Float16 xl[4][32*XSTR];

  const float*    zp   = (const float*)(ws + WS_Z) + c*16384;
  const _Float16* xloc = (const _Float16*)(ws + WS_XLOC);
  const _Float16* ap1  = (const _Float16*)(ws + WS_APOW + k*32768);      // A^{k+1}
  const _Float16* ap0  = (const _Float16*)(ws + WS_APOW + (k-1)*32768);  // A^{k} (k>0 only)

  half8 zf[2][4];
  #pragma unroll
  for (int mt=0;mt<2;mt++)
    #pragma unroll
    for (int kt=0;kt<4;kt++)
      zf[mt][kt] = ldg8h(zp + (wave*32+mt*16+l15)*128 + kt*32 + q*8);

  for (int nt=0;nt<8;nt++){
    int col = nt*16 + l15;
    floatx4 xt[2], xm[2];
    #pragma unroll
    for (int mt=0;mt<2;mt++)
      xt[mt] = h4f4(*(const half4v*)(xloc + (((t*8 + wave*2+mt)*8 + nt)<<8) + lane*4));
    #pragma unroll
    for (int kt=0;kt<4;kt++){
      half8 b1 = *(const half8*)(ap1 + (nt*16+l15)*128 + kt*32 + q*8);
      #pragma unroll
      for (int mt=0;mt<2;mt++) xt[mt] = MFMA16(zf[mt][kt], b1, xt[mt]);
    }
    if (k > 0){
      #pragma unroll
      for (int mt=0;mt<2;mt++)
        xm[mt] = h4f4(*(const half4v*)(xloc + ((((t-1)*8 + wave*2+mt)*8 + nt)<<8) + lane*4));
      #pragma unroll
      for (int kt=0;kt<4;kt++){
        half8 b0 = *(const half8*)(ap0 + (nt*16+l15)*128 + kt*32 + q*8);
        #pragma unroll
        for (int mt=0;mt<2;mt++) xm[mt] = MFMA16(zf[mt][kt], b0, xm[mt]);
      }
    } else {
      #pragma unroll
      for (int mt=0;mt<2;mt++)
        #pragma unroll
        for (int r=0;r<4;r++)
          xm[mt][r] = zp[(wave*32+mt*16+q*4+r)*128 + col];
    }
    #pragma unroll
    for (int mt=0;mt<2;mt++){
      #pragma unroll
      for (int r=0;r<4;r++){
        int b = wave*32 + mt*16 + q*4 + r;
        int base = t*16384 + b*128 + col;
        float xv = xt[mt][r];
        __builtin_nontemporal_store(xv, &out[OUT_X + base]);
        __builtin_nontemporal_store(fmaxf(__builtin_nontemporal_load(&pXMIN[base])-xv, 0.f), &out[OUT_SXMIN + base]);
        __builtin_nontemporal_store(fmaxf(xv-__builtin_nontemporal_load(&pXMAX[base]), 0.f), &out[OUT_SXMAX + base]);
        __builtin_nontemporal_store(xv - xm[mt][r], &out[OUT_SDXX + base]);
        xl[wave][(mt*16+q*4+r)*XSTR + col] = (_Float16)xv;
      }
    }
  }
  // y = X_t @ W_C (same-wave LDS transpose round-trip)
  half8 xf[2][4];
  #pragma unroll
  for (int mt=0;mt<2;mt++)
    #pragma unroll
    for (int kt=0;kt<4;kt++)
      xf[mt][kt] = *(const half8*)(&xl[wave][(mt*16+l15)*XSTR + kt*32 + q*8]);
  const _Float16* wc = (const _Float16*)(ws + WS_WC);
  #pragma unroll
  for (int ny=0;ny<4;ny++){
    floatx4 ya[2];
    ya[0][0]=ya[0][1]=ya[0][2]=ya[0][3]=0.f; ya[1]=ya[0];
    #pragma unroll
    for (int kt=0;kt<4;kt++){
      half8 wcf = *(const half8*)(wc + (ny*16+l15)*128 + kt*32 + q*8);
      #pragma unroll
      for (int mt=0;mt<2;mt++) ya[mt] = MFMA16(xf[mt][kt], wcf, ya[mt]);
    }
    #pragma unroll
    for (int mt=0;mt<2;mt++)
      #pragma unroll
      for (int r=0;r<4;r++){
        int b = wave*32 + mt*16 + q*4 + r;
        __builtin_nontemporal_store(ya[mt][r], &out[OUT_Y + t*8192 + b*64 + ny*16+l15]);
      }
  }
}

// =====================================================================
extern "C" void kernel_launch(void* const* d_in, const int* in_sizes, int n_in,
                              void* d_out, int out_size, void* d_ws, size_t ws_size,
                              hipStream_t stream) {
  (void)in_sizes; (void)n_in; (void)out_size; (void)ws_size;
  const float* Ym     = (const float*)d_in[0];
  const float* M_flow = (const float*)d_in[1];
  const float* DT     = (const float*)d_in[2];
  const float* D      = (const float*)d_in[3];
  const float* XMIN   = (const float*)d_in[4];
  const float* XMAX   = (const float*)d_in[5];
  const float* UMIN   = (const float*)d_in[6];
  const float* UMAX   = (const float*)d_in[7];
  const float* x0c    = (const float*)d_in[8];
  const float* U_A    = (const float*)d_in[9];
  const float* sig_A  = (const float*)d_in[10];
  const float* V_A    = (const float*)d_in[11];
  const float* U_C    = (const float*)d_in[12];
  const float* sig_C  = (const float*)d_in[13];
  const float* V_C    = (const float*)d_in[14];
  const float* w_E    = (const float*)d_in[15];
  const float* s_E    = (const float*)d_in[16];
  const float* w_B    = (const float*)d_in[17];
  const float* W_hf   = (const float*)d_in[18];
  const float* W_ih   = (const float*)d_in[19];
  const float* W_hh   = (const float*)d_in[20];
  const float* dxmin  = (const float*)d_in[21];
  const float* dxmax  = (const float*)d_in[22];
  char*  ws  = (char*)d_ws;
  float* out = (float*)d_out;

  hipLaunchKernelGGL(k1_weights, dim3(192), dim3(256), 0, stream,
                     U_A, sig_A, V_A, U_C, sig_C, V_C, w_E, s_E, w_B, W_hf,
                     Ym, W_ih, W_hh, ws);
  hipLaunchKernelGGL(k1b_finalize, dim3(1), dim3(256), 0, stream, x0c, ws, out);
  hipLaunchKernelGGL(k3_forcing, dim3(1025), dim3(256), 0, stream,
                     M_flow, DT, D, UMIN, UMAX, dxmin, dxmax, ws, out);
  hipLaunchKernelGGL(k5a_pass1, dim3(512), dim3(64), 0, stream, ws);
  hipLaunchKernelGGL(k5b_boundary, dim3(8), dim3(64), 0, stream, ws);
  hipLaunchKernelGGL(k6_epilogue, dim3(1024), dim3(256), 0, stream, XMIN, XMAX, ws, out);
}